// Round 21
// baseline (364.866 us; speedup 1.0000x reference)
//
#include <hip/hip_runtime.h>
#include <hip/hip_bf16.h>
#include <math.h>

#define RR 64
#define CC 32
#define NPTS (4*262144)

typedef __attribute__((ext_vector_type(8))) short short8;
typedef __attribute__((ext_vector_type(4))) float f32x4;
typedef __attribute__((ext_vector_type(16))) float f32x16;
typedef __attribute__((ext_vector_type(4))) unsigned int u32x4;

static __device__ inline ushort f2bf(float x) {
    return __builtin_bit_cast(ushort, __float2bfloat16(x));
}
static __device__ inline uint32_t pk2(float a, float b) {
    return (uint32_t)f2bf(a) | ((uint32_t)f2bf(b) << 16);
}
static __device__ inline f32x4 relu4(f32x4 v) {
    f32x4 z = {0.f, 0.f, 0.f, 0.f};
    return __builtin_elementwise_max(v, z);
}
static __device__ inline float hsum4(f32x4 v) {
    return (v[0] + v[1]) + (v[2] + v[3]);
}

// Full scheduler wall: prevents cross-region load hoisting that inflates
// register pressure past the 128 cap (R19 spill -> R20 fix, verified).
#define SWALL __builtin_amdgcn_sched_barrier(0)

// ws layout:
//   float  Pcl[3*64*64*32]   @ 0          channel-last fp32 planes [p][y][x][ch]
//   ushort W1T[24576]        @ 393216 f   layer1 A-frags [jt<8][kk<6][lane][e]  (32x32x16)
//                                         jt 0-3 = density half, jt 4-7 = rgb half
//   ushort W2T[16384]        follows      layer2 A-frags [jt2<4][kk<8][lane][e]
//   float  CWS[896]          @ 413696     BC[256]=db1|rb1 | db2[128] | dW3[128] | rW2[384]
// LDS per block = W1-density (24576 B) + W2T (32768 B) = 57344 B
//   -> 2 blocks/CU co-resident (114688 B << 160 KiB; 2x81920 failed in R8/R20).
// W1-rgb (24 KB) + CWS read from global: L2-hot, coalesced, latency under MFMA.
//
// 32x32x16 fragment layouts (HW-verified m74/m101; absmax-verified R18/R19/R20):
//   A[row][k]: row = lane&31, k = 8*(lane>>5) + e
//   B[k][col]: col = lane&31, k = 8*(lane>>5) + e
//   C/D:       col = lane&31, row = (reg&3) + 8*(reg>>2) + 4*(lane>>5)

__global__ void prepass(const float* __restrict__ planes,
                        const float* __restrict__ dW1, const float* __restrict__ rW1,
                        const float* __restrict__ dW2,
                        const float* __restrict__ db1, const float* __restrict__ rb1,
                        const float* __restrict__ db2, const float* __restrict__ dW3,
                        const float* __restrict__ rW2,
                        float* __restrict__ ws) {
    int tid = blockIdx.x * blockDim.x + threadIdx.x;
    ushort* W1T = (ushort*)(ws + 393216);
    ushort* W2T = W1T + 24576;
    float*  CWS = ws + 393216 + 20480;

    if (tid < 3 * CC * RR * RR) {
        int x = tid % RR, y = (tid / RR) % RR, ch = (tid / (RR * RR)) % CC, p = tid / (CC * RR * RR);
        ws[((p * RR + y) * RR + x) * CC + ch] = planes[tid];
    }
    if (tid < 24576) {   // W1T: tid = ((jt*6+kk)*64 + l)*8 + e
        int e = tid & 7, l = (tid >> 3) & 63, rem = tid >> 9;
        int kk = rem % 6, jt = rem / 6;
        int j = jt * 32 + (l & 31);
        int k = kk * 16 + (l >> 5) * 8 + e;       // k < 96
        float v = (j < 128) ? dW1[j * 96 + k] : rW1[(j - 128) * 96 + k];
        W1T[tid] = f2bf(v);
    }
    if (tid < 16384) {   // W2T: tid = ((jt2*8+kk)*64 + l)*8 + e
        int e = tid & 7, l = (tid >> 3) & 63, rem = tid >> 9;
        int kk = rem & 7, jt2 = rem >> 3;
        int j2 = jt2 * 32 + (l & 31);
        int k = kk * 16 + (l >> 5) * 8 + e;       // k < 128
        W2T[tid] = f2bf(dW2[j2 * 128 + k]);
    }
    if (tid < 256) CWS[tid]       = (tid < 128) ? db1[tid] : rb1[tid - 128];
    if (tid < 128) CWS[256 + tid] = db2[tid];
    if (tid < 128) CWS[384 + tid] = dW3[tid];
    if (tid < 384) CWS[512 + tid] = rW2[tid];
}

// Bilinear-sample 8 channels (chbase..chbase+7) of one plane at (cx,cy),
// packed as a bf16 MFMA B-fragment. Packed-f32 interp.
static __device__ inline short8 sample_frag(const float* __restrict__ P,
                                            int plane_base, float cx, float cy, int chbase) {
    float ix = (cx + 1.0f) * 31.5f; ix = fminf(fmaxf(ix, 0.0f), 63.0f);
    float iy = (cy + 1.0f) * 31.5f; iy = fminf(fmaxf(iy, 0.0f), 63.0f);
    int x0 = (int)ix, y0 = (int)iy;
    int x1 = min(x0 + 1, 63), y1 = min(y0 + 1, 63);
    float wx = ix - (float)x0, wy = iy - (float)y0;
    float w00 = (1.0f - wx) * (1.0f - wy), w01 = wx * (1.0f - wy);
    float w10 = (1.0f - wx) * wy,          w11 = wx * wy;
    int b00 = plane_base + (y0 * 64 + x0) * 32 + chbase;
    int b01 = plane_base + (y0 * 64 + x1) * 32 + chbase;
    int b10 = plane_base + (y1 * 64 + x0) * 32 + chbase;
    int b11 = plane_base + (y1 * 64 + x1) * 32 + chbase;
    f32x4 a0 = *(const f32x4*)(P + b00), a1 = *(const f32x4*)(P + b00 + 4);
    f32x4 c0 = *(const f32x4*)(P + b01), c1 = *(const f32x4*)(P + b01 + 4);
    f32x4 d0 = *(const f32x4*)(P + b10), d1 = *(const f32x4*)(P + b10 + 4);
    f32x4 e0 = *(const f32x4*)(P + b11), e1 = *(const f32x4*)(P + b11 + 4);
    f32x4 flo = a0 * w00 + c0 * w01 + d0 * w10 + e0 * w11;   // v_pk_fma_f32
    f32x4 fhi = a1 * w00 + c1 * w01 + d1 * w10 + e1 * w11;
    u32x4 uu;
    uu[0] = pk2(flo[0], flo[1]); uu[1] = pk2(flo[2], flo[3]);
    uu[2] = pk2(fhi[0], fhi[1]); uu[3] = pk2(fhi[2], fhi[3]);
    return __builtin_bit_cast(short8, uu);
}

#define MFMA32(a, b, c) __builtin_amdgcn_mfma_f32_32x32x16_bf16((a), (b), (c), 0, 0, 0)
#define ZACC {0.f,0.f,0.f,0.f,0.f,0.f,0.f,0.f,0.f,0.f,0.f,0.f,0.f,0.f,0.f,0.f}

// Density layer-1 j-tile (math verified R18-R20): 6 MFMAs (K=96) -> relu ->
// pk2 -> one shfl_xor(32) k-half exchange -> two layer-2 B-frags.
#define DJT(jt, BLO, BHI) { \
    const ushort* wa_ = W1L + (jt) * 3072 + lane * 8; \
    f32x16 acc_ = ZACC; \
    acc_ = MFMA32(*(const short8*)(wa_),        bf0, acc_); \
    acc_ = MFMA32(*(const short8*)(wa_ + 512),  bf1, acc_); \
    acc_ = MFMA32(*(const short8*)(wa_ + 1024), bf2, acc_); \
    acc_ = MFMA32(*(const short8*)(wa_ + 1536), bf3, acc_); \
    acc_ = MFMA32(*(const short8*)(wa_ + 2048), bf4, acc_); \
    acc_ = MFMA32(*(const short8*)(wa_ + 2560), bf5, acc_); \
    int jb_ = 32 * (jt) + h4; \
    { \
        f32x4 av0_ = {acc_[0], acc_[1], acc_[2], acc_[3]}; \
        f32x4 av1_ = {acc_[4], acc_[5], acc_[6], acc_[7]}; \
        f32x4 v0_ = relu4(av0_ + *(const f32x4*)(Cl + jb_)); \
        f32x4 v1_ = relu4(av1_ + *(const f32x4*)(Cl + jb_ + 8)); \
        unsigned m0_ = pk2(v0_[0], v0_[1]), m1_ = pk2(v0_[2], v0_[3]); \
        unsigned m2_ = pk2(v1_[0], v1_[1]), m3_ = pk2(v1_[2], v1_[3]); \
        unsigned r0_ = __shfl_xor(m0_, 32, 64), r1_ = __shfl_xor(m1_, 32, 64); \
        unsigned r2_ = __shfl_xor(m2_, 32, 64), r3_ = __shfl_xor(m3_, 32, 64); \
        u32x4 lo_; \
        lo_[0] = h ? r2_ : m0_;  lo_[1] = h ? r3_ : m1_; \
        lo_[2] = h ? m2_ : r0_;  lo_[3] = h ? m3_ : r1_; \
        BLO = __builtin_bit_cast(short8, lo_); \
    } \
    { \
        f32x4 av2_ = {acc_[8],  acc_[9],  acc_[10], acc_[11]}; \
        f32x4 av3_ = {acc_[12], acc_[13], acc_[14], acc_[15]}; \
        f32x4 v2_ = relu4(av2_ + *(const f32x4*)(Cl + jb_ + 16)); \
        f32x4 v3_ = relu4(av3_ + *(const f32x4*)(Cl + jb_ + 24)); \
        unsigned m4_ = pk2(v2_[0], v2_[1]), m5_ = pk2(v2_[2], v2_[3]); \
        unsigned m6_ = pk2(v3_[0], v3_[1]), m7_ = pk2(v3_[2], v3_[3]); \
        unsigned r4_ = __shfl_xor(m4_, 32, 64), r5_ = __shfl_xor(m5_, 32, 64); \
        unsigned r6_ = __shfl_xor(m6_, 32, 64), r7_ = __shfl_xor(m7_, 32, 64); \
        u32x4 hi_; \
        hi_[0] = h ? r6_ : m4_;  hi_[1] = h ? r7_ : m5_; \
        hi_[2] = h ? m6_ : r4_;  hi_[3] = h ? m7_ : r5_; \
        BHI = __builtin_bit_cast(short8, hi_); \
    } }

// Launch-bounds ledger (2nd arg = min BLOCKS/CU on this toolchain):
// (512,4)/(1024,4)/(1024,1) -> 64-VGPR pin; (512,2) -> 128 (verified);
// (512,1) -> 256. This kernel: 84 regs measured (R20) -> (512,2).
__global__ __launch_bounds__(512, 2)
void nerf_mfma(const float* __restrict__ points, const float* __restrict__ ws,
               const float* __restrict__ db3g, const float* __restrict__ rb2g,
               float* __restrict__ rgb_out, float* __restrict__ den_out) {
    // LDS = W1-density + W2T = 57344 B -> 2 blocks/CU (114688 << 160 KiB).
    __shared__ __align__(16) ushort SB[28672];

    const float*  P   = ws;
    const float*  Cl  = ws + 413696;                       // BC|db2|dW3|rW2 (global)
    const ushort* W1G = (const ushort*)(ws + 393216) + 12288;  // rgb-half A-frags (global)
    int tid = threadIdx.x;

    {   // stage W1-density (1536 vec16) + W2T (2048 vec16) to LDS
        const u32x4* s1 = (const u32x4*)(ws + 393216);         // W1T start
        const u32x4* s2 = (const u32x4*)((const ushort*)(ws + 393216) + 24576); // W2T
        u32x4* d1 = (u32x4*)SB;
        u32x4* d2 = (u32x4*)(SB + 12288);
        for (int j = tid; j < 1536; j += 512) d1[j] = s1[j];
        for (int j = tid; j < 2048; j += 512) d2[j] = s2[j];
    }
    __syncthreads();

    const ushort* W1L = SB;             // density A-frags, jt 0-3 (12288 ushorts)
    const ushort* W2L = SB + 12288;     // layer2 A-frags (16384 ushorts)

    int wid = tid >> 6, lane = tid & 63;
    int p5 = lane & 31;          // point column
    int h  = lane >> 5;          // k-half
    int h8 = 8 * h, h4 = 4 * h;
    int gw = blockIdx.x * 8 + wid;    // 16384 waves, 2 tiles each, 32 pts/tile

    float b3  = db3g[0];
    float rb0 = rb2g[0], rb1v = rb2g[1], rb2v = rb2g[2];

    #pragma unroll 1
    for (int it = 0; it < 2; ++it) {
        int pt = (gw * 2 + it) * 32 + p5;
        float x = points[pt * 3 + 0], y = points[pt * 3 + 1], z = points[pt * 3 + 2];

        // ---- features: 6 K-chunk B-frags for THIS lane's point ----
        short8 bf0 = sample_frag(P, 0,      x, y, h8);
        short8 bf1 = sample_frag(P, 0,      x, y, 16 + h8);
        short8 bf2 = sample_frag(P, 131072, x, z, h8);
        short8 bf3 = sample_frag(P, 131072, x, z, 16 + h8);
        short8 bf4 = sample_frag(P, 262144, y, z, h8);
        short8 bf5 = sample_frag(P, 262144, y, z, 16 + h8);

        // ---- layer1 rgb half (jt = 4..7): A-frags from GLOBAL (L2-hot) ----
        f32x4 rc0 = {0.f,0.f,0.f,0.f}, rc1 = {0.f,0.f,0.f,0.f}, rc2 = {0.f,0.f,0.f,0.f};
        #pragma unroll 1
        for (int jt = 4; jt < 8; ++jt) {
            const ushort* wa = W1G + (jt - 4) * 3072 + lane * 8;
            f32x16 acc = ZACC;
            acc = MFMA32(*(const short8*)(wa),        bf0, acc);
            acc = MFMA32(*(const short8*)(wa + 512),  bf1, acc);
            acc = MFMA32(*(const short8*)(wa + 1024), bf2, acc);
            acc = MFMA32(*(const short8*)(wa + 1536), bf3, acc);
            acc = MFMA32(*(const short8*)(wa + 2048), bf4, acc);
            acc = MFMA32(*(const short8*)(wa + 2560), bf5, acc);
            int jb = 32 * jt + h4;            // absolute j (BC index)
            int jo = 32 * (jt - 4) + h4;      // j-128 (rW2 index)
            #pragma unroll
            for (int q = 0; q < 4; ++q) {
                f32x4 av = {acc[4*q+0], acc[4*q+1], acc[4*q+2], acc[4*q+3]};
                f32x4 bb = *(const f32x4*)(Cl + jb + 8 * q);
                f32x4 v  = relu4(av + bb);
                f32x4 w0 = *(const f32x4*)(Cl + 512 + jo + 8 * q);
                f32x4 w1 = *(const f32x4*)(Cl + 640 + jo + 8 * q);
                f32x4 w2 = *(const f32x4*)(Cl + 768 + jo + 8 * q);
                rc0 += w0 * v; rc1 += w1 * v; rc2 += w2 * v;
            }
        }
        {
            float v0 = hsum4(rc0), v1 = hsum4(rc1), v2 = hsum4(rc2);
            v0 += __shfl_xor(v0, 32, 64);
            v1 += __shfl_xor(v1, 32, 64);
            v2 += __shfl_xor(v2, 32, 64);
            if (h == 0) {
                rgb_out[pt * 3 + 0] = 1.0f / (1.0f + expf(-(v0 + rb0)));
                rgb_out[pt * 3 + 1] = 1.0f / (1.0f + expf(-(v1 + rb1v)));
                rgb_out[pt * 3 + 2] = 1.0f / (1.0f + expf(-(v2 + rb2v)));
            }
        }
        SWALL;   // rgb region fully retired before density region's loads

        // ---- layer1 density half (jt = 0..3, LDS) -> 8 layer-2 B-frags ----
        short8 c0, c1, c2, c3, c4, c5, c6, c7;
        DJT(0, c0, c1) SWALL;
        DJT(1, c2, c3) SWALL;
        DJT(2, c4, c5) SWALL;
        DJT(3, c6, c7) SWALL;

        // ---- layer2 (K=128, 8 chunks, LDS) + density fold, in-lane ----
        f32x4 d4 = {0.f,0.f,0.f,0.f};
        #pragma unroll 1
        for (int jt2 = 0; jt2 < 4; ++jt2) {
            const ushort* wa = W2L + jt2 * 4096 + lane * 8;
            f32x16 acc = ZACC;
            acc = MFMA32(*(const short8*)(wa),        c0, acc);
            acc = MFMA32(*(const short8*)(wa + 512),  c1, acc);
            acc = MFMA32(*(const short8*)(wa + 1024), c2, acc);
            acc = MFMA32(*(const short8*)(wa + 1536), c3, acc);
            acc = MFMA32(*(const short8*)(wa + 2048), c4, acc);
            acc = MFMA32(*(const short8*)(wa + 2560), c5, acc);
            acc = MFMA32(*(const short8*)(wa + 3072), c6, acc);
            acc = MFMA32(*(const short8*)(wa + 3584), c7, acc);
            int jb = 32 * jt2 + h4;
            #pragma unroll
            for (int q = 0; q < 4; ++q) {
                f32x4 av = {acc[4*q+0], acc[4*q+1], acc[4*q+2], acc[4*q+3]};
                f32x4 bb = *(const f32x4*)(Cl + 256 + jb + 8 * q);
                f32x4 w3 = *(const f32x4*)(Cl + 384 + jb + 8 * q);
                d4 += w3 * relu4(av + bb);
            }
        }
        {
            float dv = hsum4(d4);
            dv += __shfl_xor(dv, 32, 64);
            dv += b3;
            float sp = fmaxf(dv, 0.0f) + log1pf(expf(-fabsf(dv)));
            if (h == 0) den_out[pt] = sp;
        }
    }
}

extern "C" void kernel_launch(void* const* d_in, const int* in_sizes, int n_in,
                              void* d_out, int out_size, void* d_ws, size_t ws_size,
                              hipStream_t stream) {
    const float* points = (const float*)d_in[0];
    const float* planes = (const float*)d_in[1];
    const float* dW1    = (const float*)d_in[2];
    const float* db1    = (const float*)d_in[3];
    const float* dW2    = (const float*)d_in[4];
    const float* db2    = (const float*)d_in[5];
    const float* dW3    = (const float*)d_in[6];
    const float* db3    = (const float*)d_in[7];
    const float* rW1    = (const float*)d_in[8];
    const float* rb1    = (const float*)d_in[9];
    const float* rW2    = (const float*)d_in[10];
    const float* rb2    = (const float*)d_in[11];

    float* out     = (float*)d_out;
    float* rgb_out = out;                 // 3*NPTS floats
    float* den_out = out + 3 * NPTS;      // NPTS floats
    float* ws      = (float*)d_ws;

    prepass<<<1536, 256, 0, stream>>>(planes, dW1, rW1, dW2, db1, rb1,
                                      db2, dW3, rW2, ws);
    nerf_mfma<<<2048, 512, 0, stream>>>(points, ws, db3, rb2, rgb_out, den_out);
}

// Round 22
// 213.672 us; speedup vs baseline: 1.7076x; 1.7076x over previous
//
#include <hip/hip_runtime.h>
#include <hip/hip_bf16.h>
#include <math.h>

#define RR 64
#define CC 32
#define NPTS (4*262144)

typedef __attribute__((ext_vector_type(8))) short short8;
typedef __attribute__((ext_vector_type(4))) float f32x4;
typedef __attribute__((ext_vector_type(4))) unsigned int u32x4;

static __device__ inline ushort f2bf(float x) {
    return __builtin_bit_cast(ushort, __float2bfloat16(x));
}
static __device__ inline uint32_t pk2(float a, float b) {
    return (uint32_t)f2bf(a) | ((uint32_t)f2bf(b) << 16);
}
static __device__ inline f32x4 relu4(f32x4 v) {
    f32x4 z = {0.f, 0.f, 0.f, 0.f};
    return __builtin_elementwise_max(v, z);
}
static __device__ inline float hsum4(f32x4 v) {
    return (v[0] + v[1]) + (v[2] + v[3]);
}

// ws layout:
//   float  Pcl[3*64*64*32]   @ 0          channel-last fp32 planes [p][y][x][ch]
//   ushort W1T[24576]        @ 393216 f   layer1 A-frag table [nt][p][lane][e]
//   ushort W2T[16384]        follows      layer2 A-frag table [nt2][kt2][lane][e]
//   float  CWS[896]          follows      BC[256]=db1|rb1 | db2[128] | dW3[128] | rW2[384]
// W1T..CWS = 85504 B, staged to LDS once per block.

__global__ void prepass(const float* __restrict__ planes,
                        const float* __restrict__ dW1, const float* __restrict__ rW1,
                        const float* __restrict__ dW2,
                        const float* __restrict__ db1, const float* __restrict__ rb1,
                        const float* __restrict__ db2, const float* __restrict__ dW3,
                        const float* __restrict__ rW2,
                        float* __restrict__ ws) {
    int tid = blockIdx.x * blockDim.x + threadIdx.x;
    ushort* W1T = (ushort*)(ws + 393216);
    ushort* W2T = W1T + 24576;
    float*  CWS = ws + 393216 + 20480;

    if (tid < 3 * CC * RR * RR) {
        int x = tid % RR, y = (tid / RR) % RR, ch = (tid / (RR * RR)) % CC, p = tid / (CC * RR * RR);
        ws[((p * RR + y) * RR + x) * CC + ch] = planes[tid];
    }
    if (tid < 24576) {   // W1T: tid = ((nt*3+p)*64 + l)*8 + e
        int e = tid & 7, l = (tid >> 3) & 63, rem = tid >> 9;
        int p = rem % 3, nt = rem / 3;
        int j = nt * 16 + (l & 15);
        int k = p * 32 + (l >> 4) * 8 + e;
        float v = (j < 128) ? dW1[j * 96 + k] : rW1[(j - 128) * 96 + k];
        W1T[tid] = f2bf(v);
    }
    if (tid < 16384) {   // W2T: tid = ((nt2*4+kt2)*64 + l)*8 + e
        int e = tid & 7, l = (tid >> 3) & 63, rem = tid >> 9;
        int kt2 = rem & 3, nt2 = rem >> 2;
        int j2 = nt2 * 16 + (l & 15);
        int k = kt2 * 32 + (l >> 4) * 8 + e;
        W2T[tid] = f2bf(dW2[j2 * 128 + k]);
    }
    if (tid < 256) CWS[tid]       = (tid < 128) ? db1[tid] : rb1[tid - 128];
    if (tid < 128) CWS[256 + tid] = db2[tid];
    if (tid < 128) CWS[384 + tid] = dW3[tid];
    if (tid < 384) CWS[512 + tid] = rW2[tid];
}

// Bilinear-sample 8 channels (8g..8g+7) of one plane at (cx,cy), packed as a
// bf16 MFMA B-fragment. Vector (packed-f32) interpolation arithmetic.
static __device__ inline short8 sample_frag(const float* __restrict__ P,
                                            int plane_base, float cx, float cy, int g8) {
    float ix = (cx + 1.0f) * 31.5f; ix = fminf(fmaxf(ix, 0.0f), 63.0f);
    float iy = (cy + 1.0f) * 31.5f; iy = fminf(fmaxf(iy, 0.0f), 63.0f);
    int x0 = (int)ix, y0 = (int)iy;
    int x1 = min(x0 + 1, 63), y1 = min(y0 + 1, 63);
    float wx = ix - (float)x0, wy = iy - (float)y0;
    float w00 = (1.0f - wx) * (1.0f - wy), w01 = wx * (1.0f - wy);
    float w10 = (1.0f - wx) * wy,          w11 = wx * wy;
    int b00 = plane_base + (y0 * 64 + x0) * 32 + g8;
    int b01 = plane_base + (y0 * 64 + x1) * 32 + g8;
    int b10 = plane_base + (y1 * 64 + x0) * 32 + g8;
    int b11 = plane_base + (y1 * 64 + x1) * 32 + g8;
    f32x4 a0 = *(const f32x4*)(P + b00), a1 = *(const f32x4*)(P + b00 + 4);
    f32x4 c0 = *(const f32x4*)(P + b01), c1 = *(const f32x4*)(P + b01 + 4);
    f32x4 d0 = *(const f32x4*)(P + b10), d1 = *(const f32x4*)(P + b10 + 4);
    f32x4 e0 = *(const f32x4*)(P + b11), e1 = *(const f32x4*)(P + b11 + 4);
    f32x4 flo = a0 * w00 + c0 * w01 + d0 * w10 + e0 * w11;   // v_pk_fma_f32
    f32x4 fhi = a1 * w00 + c1 * w01 + d1 * w10 + e1 * w11;
    u32x4 uu;
    uu[0] = pk2(flo[0], flo[1]); uu[1] = pk2(flo[2], flo[3]);
    uu[2] = pk2(fhi[0], fhi[1]); uu[3] = pk2(fhi[2], fhi[3]);
    return __builtin_bit_cast(short8, uu);
}

#define MFMA(a, b, c) __builtin_amdgcn_mfma_f32_16x16x32_bf16((a), (b), (c), 0, 0, 0)

// Density layer-1 tile nt for BOTH point halves: one A-frag read feeds 2 MFMAs.
// A-half result -> H (LDS); B-half result -> two named u32 regs (written later).
#define DNT(nt, HB0, HB1) { \
    const ushort* wp_ = W1L + (nt) * 1536 + lane * 8; \
    short8 a0_ = *(const short8*)(wp_); \
    short8 a1_ = *(const short8*)(wp_ + 512); \
    short8 a2_ = *(const short8*)(wp_ + 1024); \
    f32x4 accA_ = {0.f,0.f,0.f,0.f}, accB_ = {0.f,0.f,0.f,0.f}; \
    accA_ = MFMA(a0_, bfA0, accA_); accB_ = MFMA(a0_, bfB0, accB_); \
    accA_ = MFMA(a1_, bfA1, accA_); accB_ = MFMA(a1_, bfB1, accB_); \
    accA_ = MFMA(a2_, bfA2, accA_); accB_ = MFMA(a2_, bfB2, accB_); \
    f32x4 bb_ = *(const f32x4*)(Cl + (nt) * 16 + 4 * g); \
    f32x4 vA_ = relu4(accA_ + bb_); \
    f32x4 vB_ = relu4(accB_ + bb_); \
    uint2 wA_; \
    wA_.x = pk2(vA_[0], vA_[1]); \
    wA_.y = pk2(vA_[2], vA_[3]); \
    *(uint2*)(&H[c][16 * (nt) + 4 * g]) = wA_; \
    HB0 = pk2(vB_[0], vB_[1]); \
    HB1 = pk2(vB_[2], vB_[3]); }

#define HWB(nt, HB0, HB1) { \
    uint2 t_; t_.x = HB0; t_.y = HB1; \
    *(uint2*)(&H[c][16 * (nt) + 4 * g]) = t_; }

// DS-only scheduler wall: keeps same-wave LDS write->read program order while
// letting VALU/SALU/MFMA/VMEM (mask 0x7F) migrate across for pipelining.
#define DSWALL __builtin_amdgcn_sched_barrier(0x7F)

// NOTE: second __launch_bounds__ arg behaves as min BLOCKS per CU on this
// toolchain. (1024,1): 16 waves/CU = 4/SIMD -> 128-VGPR cap.
__global__ __launch_bounds__(1024, 1)
void nerf_mfma(const float* __restrict__ points, const float* __restrict__ ws,
               const float* __restrict__ db3g, const float* __restrict__ rb2g,
               float* __restrict__ rgb_out, float* __restrict__ den_out) {
    // LDS: weights+consts 85504 B + per-wave H 16*16*136*2 = 69632 B -> 155136 B
    __shared__ __align__(16) ushort SB[42752];
    __shared__ __align__(16) ushort Hs[16][16][136];

    const float* P = ws;
    int tid = threadIdx.x;

    // ---- stage weight tables + consts into LDS (once per block) ----
    {
        const u32x4* src = (const u32x4*)(ws + 393216);
        u32x4* dst = (u32x4*)SB;
        for (int j = tid; j < 5344; j += 1024) dst[j] = src[j];
    }
    __syncthreads();

    const ushort* W1L = SB;                          // 24576 ushorts
    const ushort* W2L = SB + 24576;                  // 16384 ushorts
    const float*  Cl  = (const float*)(SB + 40960);  // BC | db2 | dW3 | rW2

    int wid = tid >> 6, lane = tid & 63;
    int c = lane & 15, g = lane >> 4;
    int g8 = 8 * g;
    ushort (*H)[136] = Hs[wid];
    int gw = blockIdx.x * 16 + wid;     // 16384 waves, 2 tiles each, 32 pts/tile

    float b3  = db3g[0];
    float rb0 = rb2g[0], rb1v = rb2g[1], rb2v = rb2g[2];

    // ---- hoist BOTH tiles' point coordinates (independent loads; removes the
    // 2-level load dependency from tile 1's critical path) ----
    int pt0 = gw * 64;
    int ptA0 = pt0 + c,      ptB0 = pt0 + c + 16;
    int ptA1 = pt0 + 32 + c, ptB1 = pt0 + 48 + c;
    float xa0 = points[ptA0*3+0], ya0 = points[ptA0*3+1], za0 = points[ptA0*3+2];
    float xb0 = points[ptB0*3+0], yb0 = points[ptB0*3+1], zb0 = points[ptB0*3+2];
    float xa1 = points[ptA1*3+0], ya1 = points[ptA1*3+1], za1 = points[ptA1*3+2];
    float xb1 = points[ptB1*3+0], yb1 = points[ptB1*3+1], zb1 = points[ptB1*3+2];

    #pragma unroll
    for (int it = 0; it < 2; ++it) {
        int ptA = it ? ptA1 : ptA0, ptB = it ? ptB1 : ptB0;
        float xa = it ? xa1 : xa0, ya = it ? ya1 : ya0, za = it ? za1 : za0;
        float xb = it ? xb1 : xb0, yb = it ? yb1 : yb0, zb = it ? zb1 : zb0;

        // ---- features: lane (c,g) -> channels 8g..8g+7, points A, B ----
        short8 bfA0 = sample_frag(P, 0,      xa, ya, g8);
        short8 bfA1 = sample_frag(P, 131072, xa, za, g8);
        short8 bfA2 = sample_frag(P, 262144, ya, za, g8);
        short8 bfB0 = sample_frag(P, 0,      xb, yb, g8);
        short8 bfB1 = sample_frag(P, 131072, xb, zb, g8);
        short8 bfB2 = sample_frag(P, 262144, yb, zb, g8);

        // ---- layer1 rgb half (nt=8..15): fold rW2 immediately, vector accs ----
        f32x4 r0A4 = {0.f,0.f,0.f,0.f}, r1A4 = {0.f,0.f,0.f,0.f}, r2A4 = {0.f,0.f,0.f,0.f};
        f32x4 r0B4 = {0.f,0.f,0.f,0.f}, r1B4 = {0.f,0.f,0.f,0.f}, r2B4 = {0.f,0.f,0.f,0.f};
        #pragma unroll 4
        for (int nt = 8; nt < 16; ++nt) {
            const ushort* wp = W1L + nt * 1536 + lane * 8;
            short8 a0 = *(const short8*)(wp);
            short8 a1 = *(const short8*)(wp + 512);
            short8 a2 = *(const short8*)(wp + 1024);
            f32x4 accA = {0.f,0.f,0.f,0.f}, accB = {0.f,0.f,0.f,0.f};
            accA = MFMA(a0, bfA0, accA); accB = MFMA(a0, bfB0, accB);
            accA = MFMA(a1, bfA1, accA); accB = MFMA(a1, bfB1, accB);
            accA = MFMA(a2, bfA2, accA); accB = MFMA(a2, bfB2, accB);
            int jo = (nt - 8) * 16 + 4 * g;
            f32x4 bb = *(const f32x4*)(Cl + 128 + jo);
            f32x4 w0 = *(const f32x4*)(Cl + 512 + jo);
            f32x4 w1 = *(const f32x4*)(Cl + 640 + jo);
            f32x4 w2 = *(const f32x4*)(Cl + 768 + jo);
            f32x4 vA = relu4(accA + bb);
            f32x4 vB = relu4(accB + bb);
            r0A4 += w0 * vA; r0B4 += w0 * vB;
            r1A4 += w1 * vA; r1B4 += w1 * vB;
            r2A4 += w2 * vA; r2B4 += w2 * vB;
        }
        // rgb heads now (kills racc early)
        {
            float v0 = hsum4(r0A4), v1 = hsum4(r1A4), v2 = hsum4(r2A4);
            v0 += __shfl_xor(v0, 16, 64); v0 += __shfl_xor(v0, 32, 64);
            v1 += __shfl_xor(v1, 16, 64); v1 += __shfl_xor(v1, 32, 64);
            v2 += __shfl_xor(v2, 16, 64); v2 += __shfl_xor(v2, 32, 64);
            if (g == 0) {
                rgb_out[ptA * 3 + 0] = 1.0f / (1.0f + expf(-(v0 + rb0)));
                rgb_out[ptA * 3 + 1] = 1.0f / (1.0f + expf(-(v1 + rb1v)));
                rgb_out[ptA * 3 + 2] = 1.0f / (1.0f + expf(-(v2 + rb2v)));
            }
        }
        {
            float v0 = hsum4(r0B4), v1 = hsum4(r1B4), v2 = hsum4(r2B4);
            v0 += __shfl_xor(v0, 16, 64); v0 += __shfl_xor(v0, 32, 64);
            v1 += __shfl_xor(v1, 16, 64); v1 += __shfl_xor(v1, 32, 64);
            v2 += __shfl_xor(v2, 16, 64); v2 += __shfl_xor(v2, 32, 64);
            if (g == 0) {
                rgb_out[ptB * 3 + 0] = 1.0f / (1.0f + expf(-(v0 + rb0)));
                rgb_out[ptB * 3 + 1] = 1.0f / (1.0f + expf(-(v1 + rb1v)));
                rgb_out[ptB * 3 + 2] = 1.0f / (1.0f + expf(-(v2 + rb2v)));
            }
        }

        // ---- layer1 density half (nt=0..7): A -> H, B -> named regs ----
        unsigned hB0a, hB0b, hB1a, hB1b, hB2a, hB2b, hB3a, hB3b;
        unsigned hB4a, hB4b, hB5a, hB5b, hB6a, hB6b, hB7a, hB7b;
        DNT(0, hB0a, hB0b) DNT(1, hB1a, hB1b) DNT(2, hB2a, hB2b) DNT(3, hB3a, hB3b)
        DNT(4, hB4a, hB4b) DNT(5, hB5a, hB5b) DNT(6, hB6a, hB6b) DNT(7, hB7a, hB7b)

        DSWALL;   // all A-writes issue before A-reads (same-wave LDS is in-order)
        short8 b2A0 = *(const short8*)(&H[c][g8]);
        short8 b2A1 = *(const short8*)(&H[c][32 + g8]);
        short8 b2A2 = *(const short8*)(&H[c][64 + g8]);
        short8 b2A3 = *(const short8*)(&H[c][96 + g8]);
        DSWALL;   // A-reads issue before B overwrites
        HWB(0, hB0a, hB0b) HWB(1, hB1a, hB1b) HWB(2, hB2a, hB2b) HWB(3, hB3a, hB3b)
        HWB(4, hB4a, hB4b) HWB(5, hB5a, hB5b) HWB(6, hB6a, hB6b) HWB(7, hB7a, hB7b)
        DSWALL;   // B-writes issue before B-reads
        short8 b2B0 = *(const short8*)(&H[c][g8]);
        short8 b2B1 = *(const short8*)(&H[c][32 + g8]);
        short8 b2B2 = *(const short8*)(&H[c][64 + g8]);
        short8 b2B3 = *(const short8*)(&H[c][96 + g8]);
        DSWALL;   // B-reads issue before next tile's A-writes
        // (no full memory clobber here: DSWALL alone orders the cross-tile H
        // reuse; global gather loads of the next tile may hoist above.)

        // ---- layer2 + density fold: vector accumulators ----
        f32x4 dA4 = {0.f,0.f,0.f,0.f}, dB4 = {0.f,0.f,0.f,0.f};
        #pragma unroll 2
        for (int nt2 = 0; nt2 < 8; ++nt2) {
            const ushort* wp = W2L + nt2 * 2048 + lane * 8;
            short8 a0 = *(const short8*)(wp);
            short8 a1 = *(const short8*)(wp + 512);
            short8 a2 = *(const short8*)(wp + 1024);
            short8 a3 = *(const short8*)(wp + 1536);
            f32x4 accA = {0.f,0.f,0.f,0.f}, accB = {0.f,0.f,0.f,0.f};
            accA = MFMA(a0, b2A0, accA); accB = MFMA(a0, b2B0, accB);
            accA = MFMA(a1, b2A1, accA); accB = MFMA(a1, b2B1, accB);
            accA = MFMA(a2, b2A2, accA); accB = MFMA(a2, b2B2, accB);
            accA = MFMA(a3, b2A3, accA); accB = MFMA(a3, b2B3, accB);
            f32x4 bb = *(const f32x4*)(Cl + 256 + nt2 * 16 + 4 * g);
            f32x4 w3 = *(const f32x4*)(Cl + 384 + nt2 * 16 + 4 * g);
            dA4 += w3 * relu4(accA + bb);
            dB4 += w3 * relu4(accB + bb);
        }

        // ---- density heads ----
        {
            float v = hsum4(dA4);
            v += __shfl_xor(v, 16, 64); v += __shfl_xor(v, 32, 64); v += b3;
            float sp = fmaxf(v, 0.0f) + log1pf(expf(-fabsf(v)));
            if (g == 0) den_out[ptA] = sp;
        }
        {
            float v = hsum4(dB4);
            v += __shfl_xor(v, 16, 64); v += __shfl_xor(v, 32, 64); v += b3;
            float sp = fmaxf(v, 0.0f) + log1pf(expf(-fabsf(v)));
            if (g == 0) den_out[ptB] = sp;
        }
    }
}

extern "C" void kernel_launch(void* const* d_in, const int* in_sizes, int n_in,
                              void* d_out, int out_size, void* d_ws, size_t ws_size,
                              hipStream_t stream) {
    const float* points = (const float*)d_in[0];
    const float* planes = (const float*)d_in[1];
    const float* dW1    = (const float*)d_in[2];
    const float* db1    = (const float*)d_in[3];
    const float* dW2    = (const float*)d_in[4];
    const float* db2    = (const float*)d_in[5];
    const float* dW3    = (const float*)d_in[6];
    const float* db3    = (const float*)d_in[7];
    const float* rW1    = (const float*)d_in[8];
    const float* rb1    = (const float*)d_in[9];
    const float* rW2    = (const float*)d_in[10];
    const float* rb2    = (const float*)d_in[11];

    float* out     = (float*)d_out;
    float* rgb_out = out;                 // 3*NPTS floats
    float* den_out = out + 3 * NPTS;      // NPTS floats
    float* ws      = (float*)d_ws;

    prepass<<<1536, 256, 0, stream>>>(planes, dW1, rW1, dW2, db1, rb1,
                                      db2, dW3, rW2, ws);
    nerf_mfma<<<1024, 1024, 0, stream>>>(points, ws, db3, rb2, rgb_out, den_out);
}